// Round 2
// baseline (283.101 us; speedup 1.0000x reference)
//
#include <hip/hip_runtime.h>
#include <stdint.h>
#include <stddef.h>

typedef _Float16 f16;
typedef _Float16 f16x2 __attribute__((ext_vector_type(2)));
typedef _Float16 f16x8 __attribute__((ext_vector_type(8)));
typedef float    f32x4 __attribute__((ext_vector_type(4)));

#define VOCAB 32000
#define EMBD  200
#define HID   128
#define NB    64
#define NT    64
#define G4    (4*HID)   // 512 gate width

__device__ __forceinline__ float sigf(float x) {
    return __builtin_amdgcn_rcpf(1.f + __expf(-x));
}
__device__ __forceinline__ float tanhf_(float x) {
    return 1.f - 2.f * __builtin_amdgcn_rcpf(1.f + __expf(2.f * x));
}

// pack recurrent weights into f16 pairs: wp[m][p][j] = (W[2p][j], W[2p+1][j])
__global__ __launch_bounds__(256) void prep_rec(
    const float* __restrict__ U0, const float* __restrict__ W1,
    const float* __restrict__ U1, uint32_t* __restrict__ wp) {
    int idx = blockIdx.x * 256 + threadIdx.x;
    if (idx >= 3 * 64 * G4) return;
    int m = idx >> 15;
    int rem = idx & 32767;
    int p = rem >> 9, j = rem & 511;
    const float* W = (m == 0) ? U0 : (m == 1) ? W1 : U1;
    f16x2 v;
    v[0] = (f16)W[(2 * p) * G4 + j];
    v[1] = (f16)W[(2 * p + 1) * G4 + j];
    ((f16x2*)wp)[idx] = v;
}

// transpose Wout f32 [128][32000] -> WoutT f16 [32000][128]
__global__ __launch_bounds__(256) void prep_woutT(
    const float* __restrict__ Wout, f16* __restrict__ WoutT) {
    __shared__ __align__(16) f16 tile[64 * 136];   // row stride 136 f16 = 272B (16B-aligned)
    const int n0 = blockIdx.x * 64;
    const int t = threadIdx.x;
    for (int i = t; i < 64 * 128; i += 256) {
        int k = i >> 6, n = i & 63;                 // consecutive t -> consecutive n (coalesced)
        tile[n * 136 + k] = (f16)Wout[(size_t)k * VOCAB + n0 + n];
    }
    __syncthreads();
    // 64 rows x 16 uint4-chunks (8 f16 each) = full 128-element rows
    for (int i = t; i < 1024; i += 256) {
        int n = i >> 4, u = i & 15;
        *(uint4*)(WoutT + (size_t)(n0 + n) * HID + u * 8) =
            *(const uint4*)&tile[n * 136 + u * 8];
    }
}

// phase 1: z0base = emb[tokens] @ W0 + b0  (fp32)
__global__ __launch_bounds__(256) void embed_w0(
    const int* __restrict__ tokens, const float* __restrict__ emb,
    const float* __restrict__ W0, const float* __restrict__ b0,
    float* __restrict__ z0) {
    __shared__ __align__(16) float xs[EMBD * 16];   // [k][r]
    __shared__ int tok[16];
    const int t = threadIdx.x, blk = blockIdx.x;
    if (t < 16) tok[t] = tokens[blk * 16 + t];
    __syncthreads();
    for (int i = t; i < EMBD * 16; i += 256) {
        int r = i / EMBD, k = i - r * EMBD;
        xs[k * 16 + r] = emb[(size_t)tok[r] * EMBD + k];
    }
    __syncthreads();
    const int j = t * 2;
    f32x4 accA[4], accB[4];
#pragma unroll
    for (int grp = 0; grp < 4; ++grp) {
        accA[grp] = f32x4{0.f, 0.f, 0.f, 0.f};
        accB[grp] = f32x4{0.f, 0.f, 0.f, 0.f};
    }
    for (int k = 0; k < EMBD; ++k) {
        float2 w = *(const float2*)(W0 + (size_t)k * G4 + j);
        const f32x4* xv = (const f32x4*)(xs + k * 16);
#pragma unroll
        for (int grp = 0; grp < 4; ++grp) {
            f32x4 x = xv[grp];
            accA[grp] += x * w.x;
            accB[grp] += x * w.y;
        }
    }
    float bx = b0[j], by = b0[j + 1];
#pragma unroll
    for (int grp = 0; grp < 4; ++grp)
#pragma unroll
        for (int r = 0; r < 4; ++r) {
            int row = blk * 16 + grp * 4 + r;
            float2 o; o.x = accA[grp][r] + bx; o.y = accB[grp][r] + by;
            *(float2*)(z0 + (size_t)row * G4 + j) = o;
        }
}

// phase 2: sequential LSTM scan, one block per batch element, weights in registers.
// Dot products: v_dot2_f32_f16 (f16x2 pairs, fp32 accumulate).
__global__ __launch_bounds__(512, 2) void lstm_scan(
    const float* __restrict__ z0base, const uint32_t* __restrict__ wp,
    const float* __restrict__ b1, f16* __restrict__ H1) {
    const int b = blockIdx.x, t = threadIdx.x;
    const int g = t >> 7, q = t & 127, jb = q << 2;
    __shared__ __align__(16) float zpart[4][G4];
    __shared__ float zfull[G4];
    __shared__ __align__(16) f16 h0s[HID];
    __shared__ __align__(16) f16 h1s[HID];

    const f16x8* wp8 = (const f16x8*)wp;
    f16x2 wu0[64], ww1[64], wu1[64];
    const int wbase = (g * 16) * 128 + q;
#pragma unroll
    for (int kk = 0; kk < 16; ++kk) {
        *(f16x8*)&wu0[kk * 4] = wp8[0 * 8192 + wbase + kk * 128];
        *(f16x8*)&ww1[kk * 4] = wp8[1 * 8192 + wbase + kk * 128];
        *(f16x8*)&wu1[kk * 4] = wp8[2 * 8192 + wbase + kk * 128];
    }
    const float b1r = b1[t];
    float c0 = 0.f, c1 = 0.f;
    if (t < HID) { h0s[t] = (f16)0.f; h1s[t] = (f16)0.f; }
    __syncthreads();

    const float* zrow = z0base + (size_t)b * NT * G4 + t;
    f16* hout = H1 + (size_t)b * NT * HID;

    for (int step = 0; step < NT; ++step) {
        float z0t = zrow[(size_t)step * G4];
        float a0 = 0.f, a1 = 0.f, a2 = 0.f, a3 = 0.f;
        {
            f16x2 hh[16];
            const f16x8* hp = (const f16x8*)h0s + g * 4;
            *(f16x8*)&hh[0] = hp[0]; *(f16x8*)&hh[4] = hp[1];
            *(f16x8*)&hh[8] = hp[2]; *(f16x8*)&hh[12] = hp[3];
#pragma unroll
            for (int kk = 0; kk < 16; ++kk) {
                f16x2 h = hh[kk];
                a0 = __builtin_amdgcn_fdot2(wu0[kk * 4 + 0], h, a0, false);
                a1 = __builtin_amdgcn_fdot2(wu0[kk * 4 + 1], h, a1, false);
                a2 = __builtin_amdgcn_fdot2(wu0[kk * 4 + 2], h, a2, false);
                a3 = __builtin_amdgcn_fdot2(wu0[kk * 4 + 3], h, a3, false);
            }
        }
        *(f32x4*)&zpart[g][jb] = f32x4{a0, a1, a2, a3};
        __syncthreads();
        zfull[t] = z0t + zpart[0][t] + zpart[1][t] + zpart[2][t] + zpart[3][t];
        __syncthreads();
        if (t < HID) {
            float zi = zfull[t], zf = zfull[t + 128], zg = zfull[t + 256], zo = zfull[t + 384];
            c0 = sigf(zf) * c0 + sigf(zi) * tanhf_(zg);
            h0s[t] = (f16)(sigf(zo) * tanhf_(c0));
        }
        __syncthreads();
        a0 = 0.f; a1 = 0.f; a2 = 0.f; a3 = 0.f;
        {
            f16x2 hh[16];
            const f16x8* hp0 = (const f16x8*)h0s + g * 4;
            *(f16x8*)&hh[0] = hp0[0]; *(f16x8*)&hh[4] = hp0[1];
            *(f16x8*)&hh[8] = hp0[2]; *(f16x8*)&hh[12] = hp0[3];
#pragma unroll
            for (int kk = 0; kk < 16; ++kk) {
                f16x2 h = hh[kk];
                a0 = __builtin_amdgcn_fdot2(ww1[kk * 4 + 0], h, a0, false);
                a1 = __builtin_amdgcn_fdot2(ww1[kk * 4 + 1], h, a1, false);
                a2 = __builtin_amdgcn_fdot2(ww1[kk * 4 + 2], h, a2, false);
                a3 = __builtin_amdgcn_fdot2(ww1[kk * 4 + 3], h, a3, false);
            }
            const f16x8* hp1 = (const f16x8*)h1s + g * 4;
            *(f16x8*)&hh[0] = hp1[0]; *(f16x8*)&hh[4] = hp1[1];
            *(f16x8*)&hh[8] = hp1[2]; *(f16x8*)&hh[12] = hp1[3];
#pragma unroll
            for (int kk = 0; kk < 16; ++kk) {
                f16x2 h = hh[kk];
                a0 = __builtin_amdgcn_fdot2(wu1[kk * 4 + 0], h, a0, false);
                a1 = __builtin_amdgcn_fdot2(wu1[kk * 4 + 1], h, a1, false);
                a2 = __builtin_amdgcn_fdot2(wu1[kk * 4 + 2], h, a2, false);
                a3 = __builtin_amdgcn_fdot2(wu1[kk * 4 + 3], h, a3, false);
            }
        }
        *(f32x4*)&zpart[g][jb] = f32x4{a0, a1, a2, a3};
        __syncthreads();
        zfull[t] = b1r + zpart[0][t] + zpart[1][t] + zpart[2][t] + zpart[3][t];
        __syncthreads();
        if (t < HID) {
            float zi = zfull[t], zf = zfull[t + 128], zg = zfull[t + 256], zo = zfull[t + 384];
            c1 = sigf(zf) * c1 + sigf(zi) * tanhf_(zg);
            float h1v = sigf(zo) * tanhf_(c1);
            h1s[t] = (f16)h1v;
            hout[step * HID + t] = (f16)h1v;
        }
    }
}

// phase 3: out = relu(H1 @ Wout + bout) via f16 MFMA, tile 128x128, K=128 one-shot
__global__ __launch_bounds__(256) void out_gemm(
    const f16* __restrict__ H1, const f16* __restrict__ WT,
    const float* __restrict__ bout, float* __restrict__ out) {
    __shared__ __align__(16) f16 Asub[128 * 128];
    __shared__ __align__(16) f16 Bsub[128 * 128];
    const int n0 = blockIdx.x * 128;
    const int m0 = blockIdx.y * 128;
    const int t = threadIdx.x;

    const uint4* Ag = (const uint4*)(H1 + (size_t)m0 * HID);
    const uint4* Bg = (const uint4*)(WT + (size_t)n0 * HID);
#pragma unroll
    for (int i = 0; i < 8; ++i) {
        int Gr = i * 256 + t;
        int row = Gr >> 4, gg = Gr & 15;
        int d = (row << 4) | (gg ^ (row & 7));   // XOR granule swizzle (T2-style)
        ((uint4*)Asub)[d] = Ag[Gr];
        ((uint4*)Bsub)[d] = Bg[Gr];
    }
    __syncthreads();

    const int w = t >> 6, l = t & 63;
    const int wm = (w >> 1) * 64, wn = (w & 1) * 64;
    const int lr = l & 15, lk = l >> 4;
    f32x4 zero = {0.f, 0.f, 0.f, 0.f};
    f32x4 acc[4][4];
#pragma unroll
    for (int mi = 0; mi < 4; ++mi)
#pragma unroll
        for (int ni = 0; ni < 4; ++ni) acc[mi][ni] = zero;

#pragma unroll
    for (int kc = 0; kc < 4; ++kc) {
        f16x8 af[4], bf[4];
#pragma unroll
        for (int mi = 0; mi < 4; ++mi) {
            int row = wm + mi * 16 + lr;
            int gg = kc * 4 + lk;
            af[mi] = *(const f16x8*)&Asub[(row << 7) + ((gg ^ (row & 7)) << 3)];
        }
#pragma unroll
        for (int ni = 0; ni < 4; ++ni) {
            int row = wn + ni * 16 + lr;
            int gg = kc * 4 + lk;
            bf[ni] = *(const f16x8*)&Bsub[(row << 7) + ((gg ^ (row & 7)) << 3)];
        }
#pragma unroll
        for (int mi = 0; mi < 4; ++mi)
#pragma unroll
            for (int ni = 0; ni < 4; ++ni)
                acc[mi][ni] = __builtin_amdgcn_mfma_f32_16x16x32_f16(
                    af[mi], bf[ni], acc[mi][ni], 0, 0, 0);
    }

#pragma unroll
    for (int ni = 0; ni < 4; ++ni) {
        int n = n0 + wn + ni * 16 + lr;
        float bv = bout[n];
#pragma unroll
        for (int mi = 0; mi < 4; ++mi) {
            int mrow = m0 + wm + mi * 16 + lk * 4;
#pragma unroll
            for (int r = 0; r < 4; ++r) {
                float v = acc[mi][ni][r] + bv;
                out[(size_t)(mrow + r) * VOCAB + n] = v > 0.f ? v : 0.f;
            }
        }
    }
}

extern "C" void kernel_launch(void* const* d_in, const int* in_sizes, int n_in,
                              void* d_out, int out_size, void* d_ws, size_t ws_size,
                              hipStream_t stream) {
    const int*   tokens = (const int*)d_in[0];
    const float* emb  = (const float*)d_in[1];
    const float* W0   = (const float*)d_in[2];
    const float* U0   = (const float*)d_in[3];
    const float* b0   = (const float*)d_in[4];
    const float* W1   = (const float*)d_in[5];
    const float* U1   = (const float*)d_in[6];
    const float* b1   = (const float*)d_in[7];
    const float* Wout = (const float*)d_in[8];
    const float* bout = (const float*)d_in[9];
    float* out = (float*)d_out;

    // ws layout: [0, 8.39MB) = z0base f32 (phase1/2), reused as WoutT f16 (phase3)
    char* ws = (char*)d_ws;
    float*    z0base = (float*)ws;
    f16*      WoutT  = (f16*)ws;                   // aliases z0base (dead after scan)
    uint32_t* wp     = (uint32_t*)(ws + 8388608);
    f16*      H1     = (f16*)(ws + 8781824);       // total ws use ~9.4 MB

    embed_w0  <<<256, 256, 0, stream>>>(tokens, emb, W0, b0, z0base);
    prep_rec  <<<384, 256, 0, stream>>>(U0, W1, U1, wp);
    lstm_scan <<<64, 512, 0, stream>>>(z0base, wp, b1, H1);
    prep_woutT<<<500, 256, 0, stream>>>(Wout, WoutT);
    out_gemm  <<<dim3(250, 32), 256, 0, stream>>>(H1, WoutT, bout, out);
}